// Round 19
// baseline (384.685 us; speedup 1.0000x reference)
//
#include <hip/hip_runtime.h>

typedef __attribute__((ext_vector_type(8))) short bf16x8;
typedef __attribute__((ext_vector_type(4))) float f32x4;
typedef const __attribute__((address_space(3))) unsigned short* lds_cp;

#define DEVI __device__ __forceinline__

template <int N> struct IC { static constexpr int v = N; };

DEVI unsigned short f2bf(float f) {
  union { float f; unsigned u; } v; v.f = f;
  unsigned r = v.u + 0x7FFFu + ((v.u >> 16) & 1u);
  return (unsigned short)(r >> 16);
}

// global_load_lds, offset param ALWAYS 0 (it applies to BOTH global and LDS
// address — R5's NaN bug). Displacements folded into the global pointer.
DEVI void gload16(const void* g, void* l) {
  __builtin_amdgcn_global_load_lds(
      (const __attribute__((address_space(1))) unsigned int*)g,
      (__attribute__((address_space(3))) unsigned int*)l, 16, 0, 0);
}

// ds_read_b128 from a precomputed AS3 address + compile-time offset.
// Opaque to the compiler's waitcnt pass; ordering = our counted lgkmcnt +
// sched_barrier(0) (rule #18). DS queue is FIFO per wave.
template <int OFF>
DEVI bf16x8 lreadT(lds_cp p) {
  bf16x8 r;
  asm volatile("ds_read_b128 %0, %1 offset:%2" : "=v"(r) : "v"(p), "i"(OFF));
  return r;
}

// A-fragments: mi row-block step = +16 rows = +2048 B; XOR swizzle invariant
// (16 % 8 == 0) -> one base addr per kk, constant offsets (8 reads).
// NOTE (R16 lesson): 16-row read groups are exactly conflict-free under the
// slot^(row&7) swizzle; 32x32 MFMA's 32-row groups are structurally 4-way
// conflicted (only 8 slots/row) -> 16x16x32 is the right shape here.
template <int OFF>
DEVI void read_af(lds_cp a0, lds_cp a1, bf16x8 (&f)[4][2]) {
  f[0][0] = lreadT<OFF + 0>(a0);    f[0][1] = lreadT<OFF + 0>(a1);
  f[1][0] = lreadT<OFF + 2048>(a0); f[1][1] = lreadT<OFF + 2048>(a1);
  f[2][0] = lreadT<OFF + 4096>(a0); f[2][1] = lreadT<OFF + 4096>(a1);
  f[3][0] = lreadT<OFF + 6144>(a0); f[3][1] = lreadT<OFF + 6144>(a1);
}
// B-fragments (4 reads).
template <int OFF>
DEVI void read_bq(lds_cp b0, lds_cp b1, bf16x8 (&f)[2][2]) {
  f[0][0] = lreadT<OFF + 0>(b0);    f[0][1] = lreadT<OFF + 0>(b1);
  f[1][0] = lreadT<OFF + 2048>(b0); f[1][1] = lreadT<OFF + 2048>(b1);
}

#define MFMA16(a, b, c) __builtin_amdgcn_mfma_f32_16x16x32_bf16(a, b, c, 0, 0, 0)
#define LGKM(n) asm volatile("s_waitcnt lgkmcnt(" #n ")")
#define SBAR() __builtin_amdgcn_sched_barrier(0)

// ---- fused prep: x cvt (16384 blks) + weights cvt (16384) + bias (4) ----
__global__ void prep_kernel(const float* __restrict__ x,
                            const float* __restrict__ wq,
                            const float* __restrict__ wk,
                            const float* __restrict__ wv,
                            const float* __restrict__ wo,
                            const float* __restrict__ rel,
                            unsigned short* __restrict__ xb,
                            unsigned short* __restrict__ wqb,
                            float* __restrict__ bias1) {
  const int blk = blockIdx.x;
  if (blk < 16384) {
    const int i = blk * 256 + threadIdx.x;
    float4 v = ((const float4*)x)[i];
    ushort4 o;
    o.x = f2bf(v.x); o.y = f2bf(v.y); o.z = f2bf(v.z); o.w = f2bf(v.w);
    ((ushort4*)xb)[i] = o;
  } else if (blk < 32768) {
    const int i = (blk - 16384) * 256 + threadIdx.x;
    const int w = i >> 20, l = i & 1048575;
    const float* s = (w == 0) ? wq : (w == 1) ? wk : (w == 2) ? wv : wo;
    float4 v = ((const float4*)s)[l];
    ushort4 o;
    o.x = f2bf(v.x); o.y = f2bf(v.y); o.z = f2bf(v.z); o.w = f2bf(v.w);
    ((ushort4*)wqb)[i] = o;
  } else {
    const int t = (blk - 32768) * 256 + threadIdx.x;
    if (t < 1023) {
      const float* r = rel + t * 64;
      float s = 0.f;
#pragma unroll
      for (int d = 0; d < 64; ++d) s += r[d];
      bias1[t] = s * (1.44269504f / 64.0f);
    }
  }
}

// ---- 256x256 single-burst bf16 GEMM, 2 barriers/K-tile (R17, banked) -------
// C[m][n] = sum_k A[m][k]*B[n][k]. M=8192, K=2048, BK=64. 512 thr = 8 waves
// (2Mx4N); per-wave 128x64 out. LDS 128KB dbuf, XOR-slot swizzle both-sides.
// Within-XCD 2x2 supertile traversal (R17): working set 4MB ~= per-XCD L2
// (FETCH 320->237MB measured). Per tile t (buf=t&1):
//   issue 24 reads FIFO: bq0(4), afl(8), bq1(4), afh(8); stage B(t+1)->buf^1
//   LGKM(12)->Q00; LGKM(8)->Q01; LGKM(0); bar_A; stage A(t+2)->buf;
//   Q10+Q11 (32 MFMA); vmcnt(4) [keep A(t+2)]; kt>=30: vmcnt(0); bar_end.
// MODE 3: fused QKV (B=[wq;wk;wv], N=6144) -> Q,K row-major + V^T.
// MODE 0: f32 row-major (wo GEMM). NT = N/256.
template <int MODE, int NT>
__global__ __launch_bounds__(512, 2) void gemm256(
    const unsigned short* __restrict__ A, const unsigned short* __restrict__ B,
    void* __restrict__ Cout, void* __restrict__ Cout2, void* __restrict__ Cout3) {
  __shared__ unsigned short As[2][16384];
  __shared__ unsigned short Bs[2][16384];

  const int tid = threadIdx.x;
  // 2x2 supertile order within each XCD's 4xNT chunk
  const int xcd = blockIdx.x & 7, j = blockIdx.x >> 3;
  const int sj = j >> 2, u = j & 3;
  const int mt = xcd * 4 + (sj / (NT / 2)) * 2 + (u >> 1);
  const int nt = (sj % (NT / 2)) * 2 + (u & 1);
  const int m0 = mt * 256, n0 = nt * 256;
  const int lane = tid & 63, wid = tid >> 6;
  const int wr = wid >> 2, wc = wid & 3;
  const int g = lane >> 4, c = lane & 15;

  const int srow = tid >> 3, sjw = (tid & 7) ^ (srow & 7);
  const unsigned short* pA0[2];
  const unsigned short* pB0[2];
  unsigned short* lA0[2];
  unsigned short* lB0[2];
#pragma unroll
  for (int ch = 0; ch < 2; ++ch) {
    const int row = ch * 64 + srow;
    pA0[ch] = A + (size_t)(m0 + row) * 2048u + sjw * 8;
    pB0[ch] = B + (size_t)(n0 + row) * 2048u + sjw * 8;
    const int slot = ch * 512 + tid;
    lA0[ch] = &As[0][slot * 8];
    lB0[ch] = &Bs[0][slot * 8];
  }

  const int rA = wr * 128 + c;
  const int rB = wc * 64 + c;
  lds_cp aA0 = (lds_cp)&As[0][rA * 64 + (((0 + g) ^ (rA & 7)) * 8)];
  lds_cp aA1 = (lds_cp)&As[0][rA * 64 + (((4 + g) ^ (rA & 7)) * 8)];
  lds_cp aB0 = (lds_cp)&Bs[0][rB * 64 + (((0 + g) ^ (rB & 7)) * 8)];
  lds_cp aB1 = (lds_cp)&Bs[0][rB * 64 + (((4 + g) ^ (rB & 7)) * 8)];

  f32x4 acc[8][4];
#pragma unroll
  for (int i = 0; i < 8; ++i)
#pragma unroll
    for (int jj = 0; jj < 4; ++jj) acc[i][jj] = (f32x4){0.f, 0.f, 0.f, 0.f};

  bf16x8 afl[4][2], afh[4][2], bq0[2][2], bq1[2][2];

#pragma unroll
  for (int ch = 0; ch < 2; ++ch) {
    gload16(pA0[ch], lA0[ch]);
    gload16(pA0[ch] + 262144, lA0[ch] + 8192);
    gload16(pB0[ch], lB0[ch]);
    gload16(pB0[ch] + 262144, lB0[ch] + 8192);
  }
#pragma unroll
  for (int ch = 0; ch < 2; ++ch) {
    gload16(pA0[ch] + 64, lA0[ch] + 16384);
    gload16(pA0[ch] + 262144 + 64, lA0[ch] + 8192 + 16384);
  }
  asm volatile("s_waitcnt vmcnt(4)" ::: "memory");
  SBAR();
  __builtin_amdgcn_s_barrier();

  auto ktile = [&](auto B_, auto SB_, auto SA_, auto LB_, auto LA_, int kt) {
    constexpr int BOFF = decltype(B_)::v;
    constexpr int SB = decltype(SB_)::v;
    constexpr int SA = decltype(SA_)::v;
    constexpr int LB = decltype(LB_)::v;
    constexpr int LA = decltype(LA_)::v;

    read_bq<BOFF>(aB0, aB1, bq0);
    read_af<BOFF>(aA0, aA1, afl);
    read_bq<BOFF + 4096>(aB0, aB1, bq1);
    read_af<BOFF + 8192>(aA0, aA1, afh);
    if (kt + 1 < 32) {
      gload16(pB0[0] + SB, lB0[0] + LB);
      gload16(pB0[1] + SB, lB0[1] + LB);
      gload16(pB0[0] + 262144 + SB, lB0[0] + 8192 + LB);
      gload16(pB0[1] + 262144 + SB, lB0[1] + 8192 + LB);
    }

    LGKM(12);
    SBAR();
    __builtin_amdgcn_s_setprio(1);
#pragma unroll
    for (int kk = 0; kk < 2; ++kk)
#pragma unroll
      for (int mi = 0; mi < 4; ++mi)
#pragma unroll
        for (int ni = 0; ni < 2; ++ni)
          acc[mi][ni] = MFMA16(afl[mi][kk], bq0[ni][kk], acc[mi][ni]);
    __builtin_amdgcn_s_setprio(0);

    LGKM(8);
    SBAR();
    __builtin_amdgcn_s_setprio(1);
#pragma unroll
    for (int kk = 0; kk < 2; ++kk)
#pragma unroll
      for (int mi = 0; mi < 4; ++mi)
#pragma unroll
        for (int ni = 0; ni < 2; ++ni)
          acc[mi][ni + 2] = MFMA16(afl[mi][kk], bq1[ni][kk], acc[mi][ni + 2]);
    __builtin_amdgcn_s_setprio(0);

    LGKM(0);
    SBAR();
    __builtin_amdgcn_s_barrier();
    if (kt + 2 < 32) {
      gload16(pA0[0] + SA, lA0[0] + LA);
      gload16(pA0[1] + SA, lA0[1] + LA);
      gload16(pA0[0] + 262144 + SA, lA0[0] + 8192 + LA);
      gload16(pA0[1] + 262144 + SA, lA0[1] + 8192 + LA);
    }

    __builtin_amdgcn_s_setprio(1);
#pragma unroll
    for (int kk = 0; kk < 2; ++kk)
#pragma unroll
      for (int mi = 0; mi < 4; ++mi)
#pragma unroll
        for (int ni = 0; ni < 2; ++ni)
          acc[mi + 4][ni] = MFMA16(afh[mi][kk], bq0[ni][kk], acc[mi + 4][ni]);
#pragma unroll
    for (int kk = 0; kk < 2; ++kk)
#pragma unroll
      for (int mi = 0; mi < 4; ++mi)
#pragma unroll
        for (int ni = 0; ni < 2; ++ni)
          acc[mi + 4][ni + 2] = MFMA16(afh[mi][kk], bq1[ni][kk], acc[mi + 4][ni + 2]);
    __builtin_amdgcn_s_setprio(0);

    if (kt < 30) {
      asm volatile("s_waitcnt vmcnt(4)" ::: "memory");
    } else {
      asm volatile("s_waitcnt vmcnt(0)" ::: "memory");
    }
    SBAR();
    __builtin_amdgcn_s_barrier();
  };

  for (int t2 = 0; t2 < 16; ++t2) {
    ktile(IC<0>{}, IC<64>{}, IC<128>{}, IC<16384>{}, IC<0>{}, 2 * t2);
    ktile(IC<32768>{}, IC<128>{}, IC<192>{}, IC<0>{}, IC<16384>{}, 2 * t2 + 1);
#pragma unroll
    for (int ch = 0; ch < 2; ++ch) { pA0[ch] += 128; pB0[ch] += 128; }
  }

  const int rbase = m0 + wr * 128 + g * 4;
  const int cbase = n0 + wc * 64 + c;
  if (MODE == 0) {
    float* O = (float*)Cout;
#pragma unroll
    for (int mi = 0; mi < 8; ++mi)
#pragma unroll
      for (int ni = 0; ni < 4; ++ni)
#pragma unroll
        for (int rr = 0; rr < 4; ++rr)
          O[(size_t)(rbase + mi * 16 + rr) * 2048u + (cbase + ni * 16)] =
              acc[mi][ni][rr];
  } else {
    const int qsel = cbase >> 11;  // block-uniform (256-col tiles)
    if (qsel < 2) {
      unsigned short* O = (unsigned short*)(qsel == 0 ? Cout : Cout2);
#pragma unroll
      for (int mi = 0; mi < 8; ++mi)
#pragma unroll
        for (int ni = 0; ni < 4; ++ni)
#pragma unroll
          for (int rr = 0; rr < 4; ++rr)
            O[(size_t)(rbase + mi * 16 + rr) * 2048u +
              ((cbase + ni * 16) & 2047)] = f2bf(acc[mi][ni][rr]);
    } else {
      unsigned short* O = (unsigned short*)Cout3;
#pragma unroll
      for (int mi = 0; mi < 8; ++mi)
#pragma unroll
        for (int ni = 0; ni < 4; ++ni) {
          const int row = rbase + mi * 16;            // m = b*512 + s
          const int col = (cbase + ni * 16) & 2047;   // h*64 + d
          const int bq_ = row >> 9, s = row & 511;
          const int hh = col >> 6, dd = col & 63;
          ushort4 o;
          o.x = f2bf(acc[mi][ni][0]);
          o.y = f2bf(acc[mi][ni][1]);
          o.z = f2bf(acc[mi][ni][2]);
          o.w = f2bf(acc[mi][ni][3]);
          *(ushort4*)(O + ((size_t)((bq_ * 32 + hh) * 64 + dd) << 9) + s) = o;
        }
    }
  }
}

// -------- flash attention, SINGLE-buffered K/V, 4 blocks/CU -----------------
// LDS 36KB (Ksh 8 + Vsh 8 + Pb 16 + bl 4) -> 4 blocks/CU, 16 waves (was 3
// blocks @ 51KB, occupancy 30%). Per-tile stage latency is exposed within a
// block but hidden by cross-block TLP. Staging itself kept (R14: de-staging
// = uncoalesced L2 gather, +78us). No-max softmax (scores f32-safe).
__global__ __launch_bounds__(256, 4) void attn_kernel(
    const unsigned short* __restrict__ Q, const unsigned short* __restrict__ K,
    const unsigned short* __restrict__ VT, const float* __restrict__ bias1d,
    unsigned short* __restrict__ CTX) {
  __shared__ unsigned short Ksh[4096];
  __shared__ unsigned short Vsh[4096];
  __shared__ unsigned short Pb[4][2048];
  __shared__ float bl[1024];

  const int tid = threadIdx.x;
  const int wave = tid >> 6;
  const int lane = tid & 63;
  const int g = lane >> 4, c = lane & 15;

  const int logical = (blockIdx.x & 7) * 256 + (blockIdx.x >> 3);
  const int qc = logical & 3;
  const int bh = logical >> 2;
  const int b = bh >> 5, h = bh & 31;
  const int qrow0 = qc * 128 + wave * 32;

  for (int i = tid; i < 1023; i += 256) bl[i] = bias1d[i];

  bf16x8 aq[2][2];
  {
    const unsigned short* qb =
        Q + (size_t)(b * 512 + qrow0 + c) * 2048u + h * 64 + g * 8;
#pragma unroll
    for (int mi = 0; mi < 2; ++mi)
#pragma unroll
      for (int kk = 0; kk < 2; ++kk)
        aq[mi][kk] = *(const bf16x8*)(qb + mi * 16 * 2048 + kk * 32);
  }

  const unsigned short* kgb = K + (size_t)(b * 512) * 2048u + h * 64;
  const unsigned short* vgb = VT + (size_t)(bh * 64) * 512u;

  auto stage = [&](int kt) {
#pragma unroll
    for (int half = 0; half < 2; ++half) {
      const int slot = half * 256 + wave * 64 + lane;
      const int row = slot >> 3;
      const int j = (slot & 7) ^ (row & 7);
      gload16(kgb + (size_t)(kt * 64 + row) * 2048u + j * 8, &Ksh[slot * 8]);
      gload16(vgb + (size_t)row * 512u + kt * 64 + j * 8, &Vsh[slot * 8]);
    }
  };

  f32x4 o[2][4];
#pragma unroll
  for (int mi = 0; mi < 2; ++mi)
#pragma unroll
    for (int di = 0; di < 4; ++di) o[mi][di] = (f32x4){0.f, 0.f, 0.f, 0.f};
  float lreg[2][4];
#pragma unroll
  for (int mi = 0; mi < 2; ++mi)
#pragma unroll
    for (int rr = 0; rr < 4; ++rr) lreg[mi][rr] = 0.f;

  const float SSCALE = 0.125f * 1.44269504f;

  for (int kt = 0; kt < 8; ++kt) {
    stage(kt);
    __syncthreads();  // drains vmcnt(0): tile kt resident (also covers bl@kt=0)

    f32x4 s[2][4];
#pragma unroll
    for (int ni = 0; ni < 4; ++ni) {
      const unsigned short* kr = &Ksh[(ni * 16 + c) * 64];
      bf16x8 bk0 = *(const bf16x8*)(kr + ((0 + g) ^ (c & 7)) * 8);
      bf16x8 bk1 = *(const bf16x8*)(kr + ((4 + g) ^ (c & 7)) * 8);
#pragma unroll
      for (int mi = 0; mi < 2; ++mi) {
        f32x4 z = (f32x4){0.f, 0.f, 0.f, 0.f};
        z = MFMA16(aq[mi][0], bk0, z);
        z = MFMA16(aq[mi][1], bk1, z);
        s[mi][ni] = z;
      }
    }

    unsigned short* pw = &Pb[wave][0];
#pragma unroll
    for (int mi = 0; mi < 2; ++mi)
#pragma unroll
      for (int rr = 0; rr < 4; ++rr) {
        const int prow = mi * 16 + g * 4 + rr;
        const int off0 = kt * 64 + c - (qrow0 + prow) + 511;
        float e0 = __builtin_amdgcn_exp2f(s[mi][0][rr] * SSCALE + bl[off0]);
        float e1 = __builtin_amdgcn_exp2f(s[mi][1][rr] * SSCALE + bl[off0 + 16]);
        float e2 = __builtin_amdgcn_exp2f(s[mi][2][rr] * SSCALE + bl[off0 + 32]);
        float e3 = __builtin_amdgcn_exp2f(s[mi][3][rr] * SSCALE + bl[off0 + 48]);
        lreg[mi][rr] += (e0 + e1) + (e2 + e3);
        const int rx = prow * 64, sw = (c >> 3) ^ (prow & 7), cl = c & 7;
        pw[rx + ((0 ^ sw) * 8 | cl)] = f2bf(e0);
        pw[rx + ((2 ^ sw) * 8 | cl)] = f2bf(e1);
        pw[rx + ((4 ^ sw) * 8 | cl)] = f2bf(e2);
        pw[rx + ((6 ^ sw) * 8 | cl)] = f2bf(e3);
      }

#pragma unroll
    for (int kk = 0; kk < 2; ++kk) {
      bf16x8 pa0 =
          *(const bf16x8*)(pw + (0 + c) * 64 + ((kk * 4 + g) ^ (c & 7)) * 8);
      bf16x8 pa1 =
          *(const bf16x8*)(pw + (16 + c) * 64 + ((kk * 4 + g) ^ (c & 7)) * 8);
#pragma unroll
      for (int di = 0; di < 4; ++di) {
        bf16x8 vb = *(const bf16x8*)(&Vsh[(di * 16 + c) * 64 +
                                          ((kk * 4 + g) ^ (c & 7)) * 8]);
        o[0][di] = MFMA16(pa0, vb, o[0][di]);
        o[1][di] = MFMA16(pa1, vb, o[1][di]);
      }
    }
    __syncthreads();  // all reads of Ksh/Vsh done before next stage overwrite
  }

#pragma unroll
  for (int mi = 0; mi < 2; ++mi)
#pragma unroll
    for (int rr = 0; rr < 4; ++rr) {
      float l = lreg[mi][rr];
      l += __shfl_xor(l, 1);
      l += __shfl_xor(l, 2);
      l += __shfl_xor(l, 4);
      l += __shfl_xor(l, 8);
      const float rl = __builtin_amdgcn_rcpf(l);
      unsigned short* ob =
          CTX + (size_t)(b * 512 + qrow0 + mi * 16 + g * 4 + rr) * 2048u +
          h * 64 + c;
#pragma unroll
      for (int di = 0; di < 4; ++di) ob[di * 16] = f2bf(o[mi][di][rr] * rl);
    }
}

extern "C" void kernel_launch(void* const* d_in, const int* in_sizes, int n_in,
                              void* d_out, int out_size, void* d_ws,
                              size_t ws_size, hipStream_t stream) {
  const float* x = (const float*)d_in[0];
  const float* wq = (const float*)d_in[1];
  const float* wk = (const float*)d_in[2];
  const float* wv = (const float*)d_in[3];
  const float* wo = (const float*)d_in[4];
  const float* rel = (const float*)d_in[5];

  char* ws = (char*)d_ws;
  unsigned short* xb = (unsigned short*)(ws);                    // 32MB, 8192x2048
  unsigned short* wqb = (unsigned short*)(ws + 33554432);        // 8MB each; wq/wk/wv/wo CONTIGUOUS
  unsigned short* wob = wqb + 3 * 4194304;
  unsigned short* qb = (unsigned short*)(ws + 67108864);         // 32MB
  unsigned short* kb = qb + 16777216;                            // 32MB
  unsigned short* vt = kb + 16777216;                            // 32MB V^T
  float* bias1 = (float*)(ws + 167772160);                       // 4KB
  unsigned short* ctx = xb;  // alias: x_bf16 dead after QKV GEMM

  prep_kernel<<<32772, 256, 0, stream>>>(x, wq, wk, wv, wo, rel, xb, wqb,
                                         bias1);

  // fused QKV: B = [wq;wk;wv] (6144 x 2048), grid 32x24 = 768 blocks
  gemm256<3, 24><<<768, 512, 0, stream>>>(xb, wqb, qb, kb, vt);

  attn_kernel<<<2048, 256, 0, stream>>>(qb, kb, vt, bias1, ctx);

  gemm256<0, 8><<<256, 512, 0, stream>>>(ctx, wob, (float*)d_out, nullptr,
                                         nullptr);
}

// Round 20
// 327.866 us; speedup vs baseline: 1.1733x; 1.1733x over previous
//
#include <hip/hip_runtime.h>

typedef __attribute__((ext_vector_type(8))) short bf16x8;
typedef __attribute__((ext_vector_type(4))) float f32x4;
typedef const __attribute__((address_space(3))) unsigned short* lds_cp;

#define DEVI __device__ __forceinline__

template <int N> struct IC { static constexpr int v = N; };

DEVI unsigned short f2bf(float f) {
  union { float f; unsigned u; } v; v.f = f;
  unsigned r = v.u + 0x7FFFu + ((v.u >> 16) & 1u);
  return (unsigned short)(r >> 16);
}

// global_load_lds, offset param ALWAYS 0 (it applies to BOTH global and LDS
// address — R5's NaN bug). Displacements folded into the global pointer.
DEVI void gload16(const void* g, void* l) {
  __builtin_amdgcn_global_load_lds(
      (const __attribute__((address_space(1))) unsigned int*)g,
      (__attribute__((address_space(3))) unsigned int*)l, 16, 0, 0);
}

// ds_read_b128 from a precomputed AS3 address + compile-time offset.
// Opaque to the compiler's waitcnt pass; ordering = our counted lgkmcnt +
// sched_barrier(0) (rule #18). DS queue is FIFO per wave.
template <int OFF>
DEVI bf16x8 lreadT(lds_cp p) {
  bf16x8 r;
  asm volatile("ds_read_b128 %0, %1 offset:%2" : "=v"(r) : "v"(p), "i"(OFF));
  return r;
}

// A-fragments: mi row-block step = +16 rows = +2048 B; XOR swizzle invariant
// (16 % 8 == 0) -> one base addr per kk, constant offsets (8 reads).
// NOTE (R16 lesson): 16-row read groups are exactly conflict-free under the
// slot^(row&7) swizzle; 32x32 MFMA's 32-row groups are structurally 4-way
// conflicted (only 8 slots/row) -> 16x16x32 is the right shape here.
template <int OFF>
DEVI void read_af(lds_cp a0, lds_cp a1, bf16x8 (&f)[4][2]) {
  f[0][0] = lreadT<OFF + 0>(a0);    f[0][1] = lreadT<OFF + 0>(a1);
  f[1][0] = lreadT<OFF + 2048>(a0); f[1][1] = lreadT<OFF + 2048>(a1);
  f[2][0] = lreadT<OFF + 4096>(a0); f[2][1] = lreadT<OFF + 4096>(a1);
  f[3][0] = lreadT<OFF + 6144>(a0); f[3][1] = lreadT<OFF + 6144>(a1);
}
// B-fragments (4 reads).
template <int OFF>
DEVI void read_bq(lds_cp b0, lds_cp b1, bf16x8 (&f)[2][2]) {
  f[0][0] = lreadT<OFF + 0>(b0);    f[0][1] = lreadT<OFF + 0>(b1);
  f[1][0] = lreadT<OFF + 2048>(b0); f[1][1] = lreadT<OFF + 2048>(b1);
}

#define MFMA16(a, b, c) __builtin_amdgcn_mfma_f32_16x16x32_bf16(a, b, c, 0, 0, 0)
#define LGKM(n) asm volatile("s_waitcnt lgkmcnt(" #n ")")
#define SBAR() __builtin_amdgcn_sched_barrier(0)

// ---- fused prep: x cvt (16384 blks) + weights cvt (16384) + bias (4) ----
__global__ void prep_kernel(const float* __restrict__ x,
                            const float* __restrict__ wq,
                            const float* __restrict__ wk,
                            const float* __restrict__ wv,
                            const float* __restrict__ wo,
                            const float* __restrict__ rel,
                            unsigned short* __restrict__ xb,
                            unsigned short* __restrict__ wqb,
                            float* __restrict__ bias1) {
  const int blk = blockIdx.x;
  if (blk < 16384) {
    const int i = blk * 256 + threadIdx.x;
    float4 v = ((const float4*)x)[i];
    ushort4 o;
    o.x = f2bf(v.x); o.y = f2bf(v.y); o.z = f2bf(v.z); o.w = f2bf(v.w);
    ((ushort4*)xb)[i] = o;
  } else if (blk < 32768) {
    const int i = (blk - 16384) * 256 + threadIdx.x;
    const int w = i >> 20, l = i & 1048575;
    const float* s = (w == 0) ? wq : (w == 1) ? wk : (w == 2) ? wv : wo;
    float4 v = ((const float4*)s)[l];
    ushort4 o;
    o.x = f2bf(v.x); o.y = f2bf(v.y); o.z = f2bf(v.z); o.w = f2bf(v.w);
    ((ushort4*)wqb)[i] = o;
  } else {
    const int t = (blk - 32768) * 256 + threadIdx.x;
    if (t < 1023) {
      const float* r = rel + t * 64;
      float s = 0.f;
#pragma unroll
      for (int d = 0; d < 64; ++d) s += r[d];
      bias1[t] = s * (1.44269504f / 64.0f);
    }
  }
}

// ---- 256x256 single-burst bf16 GEMM, 2 barriers/K-tile (R17, banked) -------
// C[m][n] = sum_k A[m][k]*B[n][k]. M=8192, K=2048, BK=64. 512 thr = 8 waves
// (2Mx4N); per-wave 128x64 out. LDS 128KB dbuf, XOR-slot swizzle both-sides.
// Within-XCD 2x2 supertile traversal (R17): working set 4MB ~= per-XCD L2
// (FETCH 320->237MB measured). Per tile t (buf=t&1):
//   issue 24 reads FIFO: bq0(4), afl(8), bq1(4), afh(8); stage B(t+1)->buf^1
//   LGKM(12)->Q00; LGKM(8)->Q01; LGKM(0); bar_A; stage A(t+2)->buf;
//   Q10+Q11 (32 MFMA); vmcnt(4) [keep A(t+2)]; kt>=30: vmcnt(0); bar_end.
// MODE 3: fused QKV (B=[wq;wk;wv], N=6144) -> Q,K row-major + V^T.
// MODE 0: f32 row-major (wo GEMM). NT = N/256.
template <int MODE, int NT>
__global__ __launch_bounds__(512, 2) void gemm256(
    const unsigned short* __restrict__ A, const unsigned short* __restrict__ B,
    void* __restrict__ Cout, void* __restrict__ Cout2, void* __restrict__ Cout3) {
  __shared__ unsigned short As[2][16384];
  __shared__ unsigned short Bs[2][16384];

  const int tid = threadIdx.x;
  // 2x2 supertile order within each XCD's 4xNT chunk
  const int xcd = blockIdx.x & 7, j = blockIdx.x >> 3;
  const int sj = j >> 2, u = j & 3;
  const int mt = xcd * 4 + (sj / (NT / 2)) * 2 + (u >> 1);
  const int nt = (sj % (NT / 2)) * 2 + (u & 1);
  const int m0 = mt * 256, n0 = nt * 256;
  const int lane = tid & 63, wid = tid >> 6;
  const int wr = wid >> 2, wc = wid & 3;
  const int g = lane >> 4, c = lane & 15;

  const int srow = tid >> 3, sjw = (tid & 7) ^ (srow & 7);
  const unsigned short* pA0[2];
  const unsigned short* pB0[2];
  unsigned short* lA0[2];
  unsigned short* lB0[2];
#pragma unroll
  for (int ch = 0; ch < 2; ++ch) {
    const int row = ch * 64 + srow;
    pA0[ch] = A + (size_t)(m0 + row) * 2048u + sjw * 8;
    pB0[ch] = B + (size_t)(n0 + row) * 2048u + sjw * 8;
    const int slot = ch * 512 + tid;
    lA0[ch] = &As[0][slot * 8];
    lB0[ch] = &Bs[0][slot * 8];
  }

  const int rA = wr * 128 + c;
  const int rB = wc * 64 + c;
  lds_cp aA0 = (lds_cp)&As[0][rA * 64 + (((0 + g) ^ (rA & 7)) * 8)];
  lds_cp aA1 = (lds_cp)&As[0][rA * 64 + (((4 + g) ^ (rA & 7)) * 8)];
  lds_cp aB0 = (lds_cp)&Bs[0][rB * 64 + (((0 + g) ^ (rB & 7)) * 8)];
  lds_cp aB1 = (lds_cp)&Bs[0][rB * 64 + (((4 + g) ^ (rB & 7)) * 8)];

  f32x4 acc[8][4];
#pragma unroll
  for (int i = 0; i < 8; ++i)
#pragma unroll
    for (int jj = 0; jj < 4; ++jj) acc[i][jj] = (f32x4){0.f, 0.f, 0.f, 0.f};

  bf16x8 afl[4][2], afh[4][2], bq0[2][2], bq1[2][2];

#pragma unroll
  for (int ch = 0; ch < 2; ++ch) {
    gload16(pA0[ch], lA0[ch]);
    gload16(pA0[ch] + 262144, lA0[ch] + 8192);
    gload16(pB0[ch], lB0[ch]);
    gload16(pB0[ch] + 262144, lB0[ch] + 8192);
  }
#pragma unroll
  for (int ch = 0; ch < 2; ++ch) {
    gload16(pA0[ch] + 64, lA0[ch] + 16384);
    gload16(pA0[ch] + 262144 + 64, lA0[ch] + 8192 + 16384);
  }
  asm volatile("s_waitcnt vmcnt(4)" ::: "memory");
  SBAR();
  __builtin_amdgcn_s_barrier();

  auto ktile = [&](auto B_, auto SB_, auto SA_, auto LB_, auto LA_, int kt) {
    constexpr int BOFF = decltype(B_)::v;
    constexpr int SB = decltype(SB_)::v;
    constexpr int SA = decltype(SA_)::v;
    constexpr int LB = decltype(LB_)::v;
    constexpr int LA = decltype(LA_)::v;

    read_bq<BOFF>(aB0, aB1, bq0);
    read_af<BOFF>(aA0, aA1, afl);
    read_bq<BOFF + 4096>(aB0, aB1, bq1);
    read_af<BOFF + 8192>(aA0, aA1, afh);
    if (kt + 1 < 32) {
      gload16(pB0[0] + SB, lB0[0] + LB);
      gload16(pB0[1] + SB, lB0[1] + LB);
      gload16(pB0[0] + 262144 + SB, lB0[0] + 8192 + LB);
      gload16(pB0[1] + 262144 + SB, lB0[1] + 8192 + LB);
    }

    LGKM(12);
    SBAR();
    __builtin_amdgcn_s_setprio(1);
#pragma unroll
    for (int kk = 0; kk < 2; ++kk)
#pragma unroll
      for (int mi = 0; mi < 4; ++mi)
#pragma unroll
        for (int ni = 0; ni < 2; ++ni)
          acc[mi][ni] = MFMA16(afl[mi][kk], bq0[ni][kk], acc[mi][ni]);
    __builtin_amdgcn_s_setprio(0);

    LGKM(8);
    SBAR();
    __builtin_amdgcn_s_setprio(1);
#pragma unroll
    for (int kk = 0; kk < 2; ++kk)
#pragma unroll
      for (int mi = 0; mi < 4; ++mi)
#pragma unroll
        for (int ni = 0; ni < 2; ++ni)
          acc[mi][ni + 2] = MFMA16(afl[mi][kk], bq1[ni][kk], acc[mi][ni + 2]);
    __builtin_amdgcn_s_setprio(0);

    LGKM(0);
    SBAR();
    __builtin_amdgcn_s_barrier();
    if (kt + 2 < 32) {
      gload16(pA0[0] + SA, lA0[0] + LA);
      gload16(pA0[1] + SA, lA0[1] + LA);
      gload16(pA0[0] + 262144 + SA, lA0[0] + 8192 + LA);
      gload16(pA0[1] + 262144 + SA, lA0[1] + 8192 + LA);
    }

    __builtin_amdgcn_s_setprio(1);
#pragma unroll
    for (int kk = 0; kk < 2; ++kk)
#pragma unroll
      for (int mi = 0; mi < 4; ++mi)
#pragma unroll
        for (int ni = 0; ni < 2; ++ni)
          acc[mi + 4][ni] = MFMA16(afh[mi][kk], bq0[ni][kk], acc[mi + 4][ni]);
#pragma unroll
    for (int kk = 0; kk < 2; ++kk)
#pragma unroll
      for (int mi = 0; mi < 4; ++mi)
#pragma unroll
        for (int ni = 0; ni < 2; ++ni)
          acc[mi + 4][ni + 2] = MFMA16(afh[mi][kk], bq1[ni][kk], acc[mi + 4][ni + 2]);
    __builtin_amdgcn_s_setprio(0);

    if (kt < 30) {
      asm volatile("s_waitcnt vmcnt(4)" ::: "memory");
    } else {
      asm volatile("s_waitcnt vmcnt(0)" ::: "memory");
    }
    SBAR();
    __builtin_amdgcn_s_barrier();
  };

  for (int t2 = 0; t2 < 16; ++t2) {
    ktile(IC<0>{}, IC<64>{}, IC<128>{}, IC<16384>{}, IC<0>{}, 2 * t2);
    ktile(IC<32768>{}, IC<128>{}, IC<192>{}, IC<0>{}, IC<16384>{}, 2 * t2 + 1);
#pragma unroll
    for (int ch = 0; ch < 2; ++ch) { pA0[ch] += 128; pB0[ch] += 128; }
  }

  const int rbase = m0 + wr * 128 + g * 4;
  const int cbase = n0 + wc * 64 + c;
  if (MODE == 0) {
    float* O = (float*)Cout;
#pragma unroll
    for (int mi = 0; mi < 8; ++mi)
#pragma unroll
      for (int ni = 0; ni < 4; ++ni)
#pragma unroll
        for (int rr = 0; rr < 4; ++rr)
          O[(size_t)(rbase + mi * 16 + rr) * 2048u + (cbase + ni * 16)] =
              acc[mi][ni][rr];
  } else {
    const int qsel = cbase >> 11;  // block-uniform (256-col tiles)
    if (qsel < 2) {
      unsigned short* O = (unsigned short*)(qsel == 0 ? Cout : Cout2);
#pragma unroll
      for (int mi = 0; mi < 8; ++mi)
#pragma unroll
        for (int ni = 0; ni < 4; ++ni)
#pragma unroll
          for (int rr = 0; rr < 4; ++rr)
            O[(size_t)(rbase + mi * 16 + rr) * 2048u +
              ((cbase + ni * 16) & 2047)] = f2bf(acc[mi][ni][rr]);
    } else {
      unsigned short* O = (unsigned short*)Cout3;
#pragma unroll
      for (int mi = 0; mi < 8; ++mi)
#pragma unroll
        for (int ni = 0; ni < 4; ++ni) {
          const int row = rbase + mi * 16;            // m = b*512 + s
          const int col = (cbase + ni * 16) & 2047;   // h*64 + d
          const int bq_ = row >> 9, s = row & 511;
          const int hh = col >> 6, dd = col & 63;
          ushort4 o;
          o.x = f2bf(acc[mi][ni][0]);
          o.y = f2bf(acc[mi][ni][1]);
          o.z = f2bf(acc[mi][ni][2]);
          o.w = f2bf(acc[mi][ni][3]);
          *(ushort4*)(O + ((size_t)((bq_ * 32 + hh) * 64 + dd) << 9) + s) = o;
        }
    }
  }
}

// -------- flash attention, STAGED double-buffered (R13/R15/R17 — best;
// at the transcendental-pipe roofline: 4.3e9 exp2 / (1024 SIMD x 32
// lanes/cyc x 2.4GHz) = 54.7us ~= measured. R14: de-staging = uncoalesced
// L2 gather (+78us); R18: single-buffering exposes stage latency (+55us).)
__global__ __launch_bounds__(256, 3) void attn_kernel(
    const unsigned short* __restrict__ Q, const unsigned short* __restrict__ K,
    const unsigned short* __restrict__ VT, const float* __restrict__ bias1d,
    unsigned short* __restrict__ CTX) {
  __shared__ unsigned short Ksh[2][4096];
  __shared__ unsigned short Vsh[2][4096];
  __shared__ unsigned short Pb[4][2048];
  __shared__ float bl[1024];

  const int tid = threadIdx.x;
  const int wave = tid >> 6;
  const int lane = tid & 63;
  const int g = lane >> 4, c = lane & 15;

  const int logical = (blockIdx.x & 7) * 256 + (blockIdx.x >> 3);
  const int qc = logical & 3;
  const int bh = logical >> 2;
  const int b = bh >> 5, h = bh & 31;
  const int qrow0 = qc * 128 + wave * 32;

  for (int i = tid; i < 1023; i += 256) bl[i] = bias1d[i];

  bf16x8 aq[2][2];
  {
    const unsigned short* qb =
        Q + (size_t)(b * 512 + qrow0 + c) * 2048u + h * 64 + g * 8;
#pragma unroll
    for (int mi = 0; mi < 2; ++mi)
#pragma unroll
      for (int kk = 0; kk < 2; ++kk)
        aq[mi][kk] = *(const bf16x8*)(qb + mi * 16 * 2048 + kk * 32);
  }

  const unsigned short* kgb = K + (size_t)(b * 512) * 2048u + h * 64;
  const unsigned short* vgb = VT + (size_t)(bh * 64) * 512u;

  auto stage = [&](int buf, int kt) {
#pragma unroll
    for (int half = 0; half < 2; ++half) {
      const int slot = half * 256 + wave * 64 + lane;
      const int row = slot >> 3;
      const int j = (slot & 7) ^ (row & 7);
      gload16(kgb + (size_t)(kt * 64 + row) * 2048u + j * 8,
              &Ksh[buf][slot * 8]);
      gload16(vgb + (size_t)row * 512u + kt * 64 + j * 8, &Vsh[buf][slot * 8]);
    }
  };

  f32x4 o[2][4];
#pragma unroll
  for (int mi = 0; mi < 2; ++mi)
#pragma unroll
    for (int di = 0; di < 4; ++di) o[mi][di] = (f32x4){0.f, 0.f, 0.f, 0.f};
  float lreg[2][4];
#pragma unroll
  for (int mi = 0; mi < 2; ++mi)
#pragma unroll
    for (int rr = 0; rr < 4; ++rr) lreg[mi][rr] = 0.f;

  stage(0, 0);
  __syncthreads();

  const float SSCALE = 0.125f * 1.44269504f;

  for (int kt = 0; kt < 8; ++kt) {
    const int buf = kt & 1;
    if (kt < 7) stage(buf ^ 1, kt + 1);

    f32x4 s[2][4];
#pragma unroll
    for (int ni = 0; ni < 4; ++ni) {
      const unsigned short* kr = &Ksh[buf][(ni * 16 + c) * 64];
      bf16x8 bk0 = *(const bf16x8*)(kr + ((0 + g) ^ (c & 7)) * 8);
      bf16x8 bk1 = *(const bf16x8*)(kr + ((4 + g) ^ (c & 7)) * 8);
#pragma unroll
      for (int mi = 0; mi < 2; ++mi) {
        f32x4 z = (f32x4){0.f, 0.f, 0.f, 0.f};
        z = MFMA16(aq[mi][0], bk0, z);
        z = MFMA16(aq[mi][1], bk1, z);
        s[mi][ni] = z;
      }
    }

    unsigned short* pw = &Pb[wave][0];
#pragma unroll
    for (int mi = 0; mi < 2; ++mi)
#pragma unroll
      for (int rr = 0; rr < 4; ++rr) {
        const int prow = mi * 16 + g * 4 + rr;
        const int off0 = kt * 64 + c - (qrow0 + prow) + 511;
        float e0 = __builtin_amdgcn_exp2f(s[mi][0][rr] * SSCALE + bl[off0]);
        float e1 = __builtin_amdgcn_exp2f(s[mi][1][rr] * SSCALE + bl[off0 + 16]);
        float e2 = __builtin_amdgcn_exp2f(s[mi][2][rr] * SSCALE + bl[off0 + 32]);
        float e3 = __builtin_amdgcn_exp2f(s[mi][3][rr] * SSCALE + bl[off0 + 48]);
        lreg[mi][rr] += (e0 + e1) + (e2 + e3);
        const int rx = prow * 64, sw = (c >> 3) ^ (prow & 7), cl = c & 7;
        pw[rx + ((0 ^ sw) * 8 | cl)] = f2bf(e0);
        pw[rx + ((2 ^ sw) * 8 | cl)] = f2bf(e1);
        pw[rx + ((4 ^ sw) * 8 | cl)] = f2bf(e2);
        pw[rx + ((6 ^ sw) * 8 | cl)] = f2bf(e3);
      }

#pragma unroll
    for (int kk = 0; kk < 2; ++kk) {
      bf16x8 pa0 =
          *(const bf16x8*)(pw + (0 + c) * 64 + ((kk * 4 + g) ^ (c & 7)) * 8);
      bf16x8 pa1 =
          *(const bf16x8*)(pw + (16 + c) * 64 + ((kk * 4 + g) ^ (c & 7)) * 8);
#pragma unroll
      for (int di = 0; di < 4; ++di) {
        bf16x8 vb = *(const bf16x8*)(&Vsh[buf][(di * 16 + c) * 64 +
                                               ((kk * 4 + g) ^ (c & 7)) * 8]);
        o[0][di] = MFMA16(pa0, vb, o[0][di]);
        o[1][di] = MFMA16(pa1, vb, o[1][di]);
      }
    }
    __syncthreads();
  }

#pragma unroll
  for (int mi = 0; mi < 2; ++mi)
#pragma unroll
    for (int rr = 0; rr < 4; ++rr) {
      float l = lreg[mi][rr];
      l += __shfl_xor(l, 1);
      l += __shfl_xor(l, 2);
      l += __shfl_xor(l, 4);
      l += __shfl_xor(l, 8);
      const float rl = __builtin_amdgcn_rcpf(l);
      unsigned short* ob =
          CTX + (size_t)(b * 512 + qrow0 + mi * 16 + g * 4 + rr) * 2048u +
          h * 64 + c;
#pragma unroll
      for (int di = 0; di < 4; ++di) ob[di * 16] = f2bf(o[mi][di][rr] * rl);
    }
}

extern "C" void kernel_launch(void* const* d_in, const int* in_sizes, int n_in,
                              void* d_out, int out_size, void* d_ws,
                              size_t ws_size, hipStream_t stream) {
  const float* x = (const float*)d_in[0];
  const float* wq = (const float*)d_in[1];
  const float* wk = (const float*)d_in[2];
  const float* wv = (const float*)d_in[3];
  const float* wo = (const float*)d_in[4];
  const float* rel = (const float*)d_in[5];

  char* ws = (char*)d_ws;
  unsigned short* xb = (unsigned short*)(ws);                    // 32MB, 8192x2048
  unsigned short* wqb = (unsigned short*)(ws + 33554432);        // 8MB each; wq/wk/wv/wo CONTIGUOUS
  unsigned short* wob = wqb + 3 * 4194304;
  unsigned short* qb = (unsigned short*)(ws + 67108864);         // 32MB
  unsigned short* kb = qb + 16777216;                            // 32MB
  unsigned short* vt = kb + 16777216;                            // 32MB V^T
  float* bias1 = (float*)(ws + 167772160);                       // 4KB
  unsigned short* ctx = xb;  // alias: x_bf16 dead after QKV GEMM

  prep_kernel<<<32772, 256, 0, stream>>>(x, wq, wk, wv, wo, rel, xb, wqb,
                                         bias1);

  // fused QKV: B = [wq;wk;wv] (6144 x 2048), grid 32x24 = 768 blocks
  gemm256<3, 24><<<768, 512, 0, stream>>>(xb, wqb, qb, kb, vt);

  attn_kernel<<<2048, 256, 0, stream>>>(qb, kb, vt, bias1, ctx);

  gemm256<0, 8><<<256, 512, 0, stream>>>(ctx, wob, (float*)d_out, nullptr,
                                         nullptr);
}